// Round 1
// baseline (1014.885 us; speedup 1.0000x reference)
//
#include <hip/hip_runtime.h>

#define N_NODES_EXPECTED 100000

__global__ void deg_kernel(const int* __restrict__ dst, unsigned int* __restrict__ deg, int E) {
    int e = blockIdx.x * blockDim.x + threadIdx.x;
    if (e < E) atomicAdd(&deg[dst[e]], 1u);
}

__global__ void dinv_init_kernel(const unsigned int* __restrict__ deg, const float* __restrict__ x,
                                 float* __restrict__ dinv, float* __restrict__ agg1, int N) {
    int i = blockIdx.x * blockDim.x + threadIdx.x;
    if (i < N) {
        float d = (float)(deg[i] + 1u);          // +1 = self loop
        float di = 1.0f / sqrtf(d);
        dinv[i] = di;
        agg1[i] = di * di * x[i];                // self-loop contribution of layer-1 agg
    }
}

// layer-1 scatter (1 channel) + coef precompute
__global__ void scatter1_kernel(const int* __restrict__ src, const int* __restrict__ dst,
                                const float* __restrict__ dinv, const float* __restrict__ x,
                                float* __restrict__ coef, float* __restrict__ agg1, int E) {
    int e = blockIdx.x * blockDim.x + threadIdx.x;
    if (e < E) {
        int s = src[e], d = dst[e];
        float cf = dinv[s] * dinv[d];
        coef[e] = cf;
        atomicAdd(&agg1[d], cf * x[s]);
    }
}

// h1 = relu(agg1*W1 + b1); t2 = h1 @ W2 ; agg2 init = dinv^2 * t2
__global__ void fused12_kernel(const float* __restrict__ agg1, const float* __restrict__ dinv,
                               const float* __restrict__ W1, const float* __restrict__ b1,
                               const float* __restrict__ W2,
                               float* __restrict__ t2, float* __restrict__ agg2, int N) {
    __shared__ float sW1[64], sb1[64], sW2[64 * 32];
    for (int t = threadIdx.x; t < 64; t += blockDim.x) { sW1[t] = W1[t]; sb1[t] = b1[t]; }
    for (int t = threadIdx.x; t < 64 * 32; t += blockDim.x) sW2[t] = W2[t];
    __syncthreads();
    int i = blockIdx.x * 8 + (threadIdx.x >> 5);
    int c = threadIdx.x & 31;
    if (i >= N) return;
    float a = agg1[i], di = dinv[i];
    float acc = 0.f;
#pragma unroll
    for (int j = 0; j < 64; ++j) {
        float r = fmaxf(fmaf(a, sW1[j], sb1[j]), 0.f);
        acc = fmaf(r, sW2[j * 32 + c], acc);
    }
    t2[i * 32 + c] = acc;
    agg2[i * 32 + c] = di * di * acc;
}

// layer-2 scatter: 32 channels per edge
__global__ void scatter2_kernel(const int* __restrict__ src, const int* __restrict__ dst,
                                const float* __restrict__ coef, const float* __restrict__ t2,
                                float* __restrict__ agg2, int E) {
    int tid = blockIdx.x * blockDim.x + threadIdx.x;
    int e = tid >> 5;
    if (e >= E) return;
    int c = tid & 31;
    int s = src[e], d = dst[e];
    float v = coef[e] * t2[s * 32 + c];
    atomicAdd(&agg2[d * 32 + c], v);
}

// h2 = relu(agg2 + b2); t3 = h2 @ W3 ; agg3 init = dinv^2 * t3
__global__ void fused23_kernel(const float* __restrict__ agg2, const float* __restrict__ dinv,
                               const float* __restrict__ b2, const float* __restrict__ W3,
                               float* __restrict__ t3, float* __restrict__ agg3, int N) {
    __shared__ float sb2[32], sW3[32 * 16];
    for (int t = threadIdx.x; t < 32; t += blockDim.x) sb2[t] = b2[t];
    for (int t = threadIdx.x; t < 32 * 16; t += blockDim.x) sW3[t] = W3[t];
    __syncthreads();
    int i = blockIdx.x * 16 + (threadIdx.x >> 4);
    int c = threadIdx.x & 15;
    if (i >= N) return;
    float di = dinv[i];
    float acc = 0.f;
#pragma unroll
    for (int k = 0; k < 32; ++k) {
        float r = fmaxf(agg2[i * 32 + k] + sb2[k], 0.f);
        acc = fmaf(r, sW3[k * 16 + c], acc);
    }
    t3[i * 16 + c] = acc;
    agg3[i * 16 + c] = di * di * acc;
}

// layer-3 scatter: 16 channels per edge
__global__ void scatter3_kernel(const int* __restrict__ src, const int* __restrict__ dst,
                                const float* __restrict__ coef, const float* __restrict__ t3,
                                float* __restrict__ agg3, int E) {
    int tid = blockIdx.x * blockDim.x + threadIdx.x;
    int e = tid >> 4;
    if (e >= E) return;
    int c = tid & 15;
    int s = src[e], d = dst[e];
    float v = coef[e] * t3[s * 16 + c];
    atomicAdd(&agg3[d * 16 + c], v);
}

// h3 = relu(agg3 + b3); t4 = h3 @ W4 ; out init = dinv^2 * t4 + b4
__global__ void fused34_kernel(const float* __restrict__ agg3, const float* __restrict__ dinv,
                               const float* __restrict__ b3, const float* __restrict__ W4,
                               const float* __restrict__ b4,
                               float* __restrict__ t4, float* __restrict__ out, int N) {
    int i = blockIdx.x * blockDim.x + threadIdx.x;
    if (i >= N) return;
    const float4* a4 = reinterpret_cast<const float4*>(agg3 + i * 16);
    float acc = 0.f;
#pragma unroll
    for (int q = 0; q < 4; ++q) {
        float4 v = a4[q];
        acc = fmaf(fmaxf(v.x + b3[q * 4 + 0], 0.f), W4[q * 4 + 0], acc);
        acc = fmaf(fmaxf(v.y + b3[q * 4 + 1], 0.f), W4[q * 4 + 1], acc);
        acc = fmaf(fmaxf(v.z + b3[q * 4 + 2], 0.f), W4[q * 4 + 2], acc);
        acc = fmaf(fmaxf(v.w + b3[q * 4 + 3], 0.f), W4[q * 4 + 3], acc);
    }
    float di = dinv[i];
    t4[i] = acc;
    out[i] = di * di * acc + b4[0];
}

// layer-4 scatter: 1 channel, accumulate directly into d_out
__global__ void scatter4_kernel(const int* __restrict__ src, const int* __restrict__ dst,
                                const float* __restrict__ coef, const float* __restrict__ t4,
                                float* __restrict__ out, int E) {
    int e = blockIdx.x * blockDim.x + threadIdx.x;
    if (e < E) atomicAdd(&out[dst[e]], coef[e] * t4[src[e]]);
}

extern "C" void kernel_launch(void* const* d_in, const int* in_sizes, int n_in,
                              void* d_out, int out_size, void* d_ws, size_t ws_size,
                              hipStream_t stream) {
    const float* x   = (const float*)d_in[0];
    const int* eidx  = (const int*)d_in[1];
    const float* W1  = (const float*)d_in[2];
    const float* b1  = (const float*)d_in[3];
    const float* W2  = (const float*)d_in[4];
    const float* b2  = (const float*)d_in[5];
    const float* W3  = (const float*)d_in[6];
    const float* b3  = (const float*)d_in[7];
    const float* W4  = (const float*)d_in[8];
    const float* b4  = (const float*)d_in[9];
    float* out = (float*)d_out;

    const int N = in_sizes[0];          // 100000
    const int E = in_sizes[1] / 2;      // 3200000
    const int* src = eidx;
    const int* dst = eidx + E;

    // workspace layout (all 16B-aligned: N*4=400000 and E*4=12800000 are multiples of 16)
    char* ws = (char*)d_ws;
    unsigned int* deg = (unsigned int*)ws;            ws += (size_t)N * 4;
    float* dinv = (float*)ws;                         ws += (size_t)N * 4;
    float* agg1 = (float*)ws;                         ws += (size_t)N * 4;
    float* coef = (float*)ws;                         ws += (size_t)E * 4;
    float* t2   = (float*)ws;                         ws += (size_t)N * 32 * 4;
    float* agg2 = (float*)ws;                         ws += (size_t)N * 32 * 4;
    float* t3   = (float*)ws;                         ws += (size_t)N * 16 * 4;
    float* agg3 = (float*)ws;                         ws += (size_t)N * 16 * 4;
    float* t4   = (float*)ws;                         ws += (size_t)N * 4;

    const int B = 256;
    hipMemsetAsync(deg, 0, (size_t)N * 4, stream);

    deg_kernel<<<(E + B - 1) / B, B, 0, stream>>>(dst, deg, E);
    dinv_init_kernel<<<(N + B - 1) / B, B, 0, stream>>>(deg, x, dinv, agg1, N);
    scatter1_kernel<<<(E + B - 1) / B, B, 0, stream>>>(src, dst, dinv, x, coef, agg1, E);
    fused12_kernel<<<(N + 7) / 8, B, 0, stream>>>(agg1, dinv, W1, b1, W2, t2, agg2, N);
    scatter2_kernel<<<((size_t)E * 32 + B - 1) / B, B, 0, stream>>>(src, dst, coef, t2, agg2, E);
    fused23_kernel<<<(N + 15) / 16, B, 0, stream>>>(agg2, dinv, b2, W3, t3, agg3, N);
    scatter3_kernel<<<((size_t)E * 16 + B - 1) / B, B, 0, stream>>>(src, dst, coef, t3, agg3, E);
    fused34_kernel<<<(N + B - 1) / B, B, 0, stream>>>(agg3, dinv, b3, W4, b4, t4, out, N);
    scatter4_kernel<<<(E + B - 1) / B, B, 0, stream>>>(src, dst, coef, t4, out, E);
}

// Round 2
// 542.101 us; speedup vs baseline: 1.8721x; 1.8721x over previous
//
#include <hip/hip_runtime.h>

// ---------------- degree histogram ----------------
__global__ void deg_kernel(const int* __restrict__ dst, unsigned int* __restrict__ deg, int E) {
    int e = blockIdx.x * blockDim.x + threadIdx.x;
    if (e < E) atomicAdd(&deg[dst[e]], 1u);
}

// ---------------- exclusive scan of deg -> off (3-kernel hierarchical) ----------------
__global__ void chunk_sum_kernel(const unsigned int* __restrict__ deg, unsigned int* __restrict__ bsum, int N) {
    __shared__ unsigned int s[256];
    int i = blockIdx.x * 256 + threadIdx.x;
    unsigned int v = (i < N) ? deg[i] : 0u;
    s[threadIdx.x] = v; __syncthreads();
    for (int o = 128; o > 0; o >>= 1) {
        if (threadIdx.x < o) s[threadIdx.x] += s[threadIdx.x + o];
        __syncthreads();
    }
    if (threadIdx.x == 0) bsum[blockIdx.x] = s[0];
}

// single-block exclusive scan of block sums (nb <= 1024; N<=262144)
__global__ void scan_bsum_kernel(unsigned int* __restrict__ bsum, int nb) {
    __shared__ unsigned int s[1024];
    int t = threadIdx.x;
    unsigned int v = (t < nb) ? bsum[t] : 0u;
    s[t] = v; __syncthreads();
    for (int o = 1; o < 1024; o <<= 1) {
        unsigned int add = (t >= o) ? s[t - o] : 0u;
        __syncthreads();
        s[t] += add;
        __syncthreads();
    }
    if (t < nb) bsum[t] = s[t] - v;   // exclusive
}

__global__ void chunk_scan_kernel(const unsigned int* __restrict__ deg, const unsigned int* __restrict__ bsum,
                                  unsigned int* __restrict__ off, int N) {
    __shared__ unsigned int s[256];
    int i = blockIdx.x * 256 + threadIdx.x;
    unsigned int v = (i < N) ? deg[i] : 0u;
    s[threadIdx.x] = v; __syncthreads();
    for (int o = 1; o < 256; o <<= 1) {
        unsigned int add = (threadIdx.x >= (unsigned)o) ? s[threadIdx.x - o] : 0u;
        __syncthreads();
        s[threadIdx.x] += add;
        __syncthreads();
    }
    if (i < N) off[i] = bsum[blockIdx.x] + s[threadIdx.x] - v;  // exclusive
}

// ---------------- dinv ----------------
__global__ void dinv_kernel(const unsigned int* __restrict__ deg, float* __restrict__ dinv, int N) {
    int i = blockIdx.x * blockDim.x + threadIdx.x;
    if (i < N) dinv[i] = 1.0f / sqrtf((float)(deg[i] + 1u));  // +1 = self loop
}

// ---------------- CSR fill: csr[slot] = {src, coef} ----------------
__global__ void fill_kernel(const int* __restrict__ src, const int* __restrict__ dst,
                            const float* __restrict__ dinv, const unsigned int* __restrict__ off,
                            unsigned int* __restrict__ cur, uint2* __restrict__ csr, int E) {
    int e = blockIdx.x * blockDim.x + threadIdx.x;
    if (e >= E) return;
    int s = src[e], d = dst[e];
    unsigned int slot = off[d] + atomicAdd(&cur[d], 1u);
    uint2 rec;
    rec.x = (unsigned int)s;
    rec.y = __float_as_uint(dinv[s] * dinv[d]);
    csr[slot] = rec;
}

// ---------------- gathers ----------------
// scalar gather (layer 1): agg1[i] = dinv^2 * x[i] + sum coef*x[s]
__global__ void gather1_kernel(const uint2* __restrict__ csr, const unsigned int* __restrict__ off,
                               const unsigned int* __restrict__ deg, const float* __restrict__ dinv,
                               const float* __restrict__ x, float* __restrict__ agg1, int N) {
    int i = blockIdx.x * blockDim.x + threadIdx.x;
    if (i >= N) return;
    float di = dinv[i];
    float acc = di * di * x[i];
    unsigned int o = off[i], n = deg[i];
    unsigned int k = 0;
    for (; k + 1 < n; k += 2) {
        uint2 r0 = csr[o + k], r1 = csr[o + k + 1];
        float v0 = x[r0.x], v1 = x[r1.x];
        acc = fmaf(__uint_as_float(r0.y), v0, acc);
        acc = fmaf(__uint_as_float(r1.y), v1, acc);
    }
    if (k < n) {
        uint2 r = csr[o + k];
        acc = fmaf(__uint_as_float(r.y), x[r.x], acc);
    }
    agg1[i] = acc;
}

// 32-channel gather (layer 2): one 32-lane group per node
__global__ void gather32_kernel(const uint2* __restrict__ csr, const unsigned int* __restrict__ off,
                                const unsigned int* __restrict__ deg, const float* __restrict__ dinv,
                                const float* __restrict__ t, float* __restrict__ agg, int N) {
    int g = (blockIdx.x * blockDim.x + threadIdx.x) >> 5;
    int c = threadIdx.x & 31;
    if (g >= N) return;
    float di = dinv[g];
    float acc = di * di * t[(size_t)g * 32 + c];
    unsigned int o = off[g], n = deg[g];
    unsigned int k = 0;
    for (; k + 1 < n; k += 2) {
        uint2 r0 = csr[o + k], r1 = csr[o + k + 1];
        float v0 = t[(size_t)r0.x * 32 + c];
        float v1 = t[(size_t)r1.x * 32 + c];
        acc = fmaf(__uint_as_float(r0.y), v0, acc);
        acc = fmaf(__uint_as_float(r1.y), v1, acc);
    }
    if (k < n) {
        uint2 r = csr[o + k];
        acc = fmaf(__uint_as_float(r.y), t[(size_t)r.x * 32 + c], acc);
    }
    agg[(size_t)g * 32 + c] = acc;
}

// 16-channel gather (layer 3): one 16-lane group per node
__global__ void gather16_kernel(const uint2* __restrict__ csr, const unsigned int* __restrict__ off,
                                const unsigned int* __restrict__ deg, const float* __restrict__ dinv,
                                const float* __restrict__ t, float* __restrict__ agg, int N) {
    int g = (blockIdx.x * blockDim.x + threadIdx.x) >> 4;
    int c = threadIdx.x & 15;
    if (g >= N) return;
    float di = dinv[g];
    float acc = di * di * t[(size_t)g * 16 + c];
    unsigned int o = off[g], n = deg[g];
    unsigned int k = 0;
    for (; k + 1 < n; k += 2) {
        uint2 r0 = csr[o + k], r1 = csr[o + k + 1];
        float v0 = t[(size_t)r0.x * 16 + c];
        float v1 = t[(size_t)r1.x * 16 + c];
        acc = fmaf(__uint_as_float(r0.y), v0, acc);
        acc = fmaf(__uint_as_float(r1.y), v1, acc);
    }
    if (k < n) {
        uint2 r = csr[o + k];
        acc = fmaf(__uint_as_float(r.y), t[(size_t)r.x * 16 + c], acc);
    }
    agg[(size_t)g * 16 + c] = acc;
}

// scalar gather (layer 4) -> out with bias
__global__ void gather4_kernel(const uint2* __restrict__ csr, const unsigned int* __restrict__ off,
                               const unsigned int* __restrict__ deg, const float* __restrict__ dinv,
                               const float* __restrict__ t4, const float* __restrict__ b4,
                               float* __restrict__ out, int N) {
    int i = blockIdx.x * blockDim.x + threadIdx.x;
    if (i >= N) return;
    float di = dinv[i];
    float acc = di * di * t4[i];
    unsigned int o = off[i], n = deg[i];
    unsigned int k = 0;
    for (; k + 1 < n; k += 2) {
        uint2 r0 = csr[o + k], r1 = csr[o + k + 1];
        float v0 = t4[r0.x], v1 = t4[r1.x];
        acc = fmaf(__uint_as_float(r0.y), v0, acc);
        acc = fmaf(__uint_as_float(r1.y), v1, acc);
    }
    if (k < n) {
        uint2 r = csr[o + k];
        acc = fmaf(__uint_as_float(r.y), t4[r.x], acc);
    }
    out[i] = acc + b4[0];
}

// ---------------- fused node-local transforms ----------------
// t2 = relu(agg1*W1 + b1) @ W2   (agg1 scalar per node)
__global__ void fused12_kernel(const float* __restrict__ agg1,
                               const float* __restrict__ W1, const float* __restrict__ b1,
                               const float* __restrict__ W2, float* __restrict__ t2, int N) {
    __shared__ float sW1[64], sb1[64], sW2[64 * 32];
    for (int t = threadIdx.x; t < 64; t += blockDim.x) { sW1[t] = W1[t]; sb1[t] = b1[t]; }
    for (int t = threadIdx.x; t < 64 * 32; t += blockDim.x) sW2[t] = W2[t];
    __syncthreads();
    int i = blockIdx.x * 8 + (threadIdx.x >> 5);
    int c = threadIdx.x & 31;
    if (i >= N) return;
    float a = agg1[i];
    float acc = 0.f;
#pragma unroll
    for (int j = 0; j < 64; ++j) {
        float r = fmaxf(fmaf(a, sW1[j], sb1[j]), 0.f);
        acc = fmaf(r, sW2[j * 32 + c], acc);
    }
    t2[(size_t)i * 32 + c] = acc;
}

// t3 = relu(agg2 + b2) @ W3
__global__ void fused23_kernel(const float* __restrict__ agg2, const float* __restrict__ b2,
                               const float* __restrict__ W3, float* __restrict__ t3, int N) {
    __shared__ float sb2[32], sW3[32 * 16];
    for (int t = threadIdx.x; t < 32; t += blockDim.x) sb2[t] = b2[t];
    for (int t = threadIdx.x; t < 32 * 16; t += blockDim.x) sW3[t] = W3[t];
    __syncthreads();
    int i = blockIdx.x * 16 + (threadIdx.x >> 4);
    int c = threadIdx.x & 15;
    if (i >= N) return;
    float acc = 0.f;
#pragma unroll
    for (int k = 0; k < 32; ++k) {
        float r = fmaxf(agg2[(size_t)i * 32 + k] + sb2[k], 0.f);
        acc = fmaf(r, sW3[k * 16 + c], acc);
    }
    t3[(size_t)i * 16 + c] = acc;
}

// t4 = relu(agg3 + b3) @ W4
__global__ void fused34_kernel(const float* __restrict__ agg3, const float* __restrict__ b3,
                               const float* __restrict__ W4, float* __restrict__ t4, int N) {
    int i = blockIdx.x * blockDim.x + threadIdx.x;
    if (i >= N) return;
    const float4* a4 = reinterpret_cast<const float4*>(agg3 + (size_t)i * 16);
    float acc = 0.f;
#pragma unroll
    for (int q = 0; q < 4; ++q) {
        float4 v = a4[q];
        acc = fmaf(fmaxf(v.x + b3[q * 4 + 0], 0.f), W4[q * 4 + 0], acc);
        acc = fmaf(fmaxf(v.y + b3[q * 4 + 1], 0.f), W4[q * 4 + 1], acc);
        acc = fmaf(fmaxf(v.z + b3[q * 4 + 2], 0.f), W4[q * 4 + 2], acc);
        acc = fmaf(fmaxf(v.w + b3[q * 4 + 3], 0.f), W4[q * 4 + 3], acc);
    }
    t4[i] = acc;
}

extern "C" void kernel_launch(void* const* d_in, const int* in_sizes, int n_in,
                              void* d_out, int out_size, void* d_ws, size_t ws_size,
                              hipStream_t stream) {
    const float* x  = (const float*)d_in[0];
    const int* eidx = (const int*)d_in[1];
    const float* W1 = (const float*)d_in[2];
    const float* b1 = (const float*)d_in[3];
    const float* W2 = (const float*)d_in[4];
    const float* b2 = (const float*)d_in[5];
    const float* W3 = (const float*)d_in[6];
    const float* b3 = (const float*)d_in[7];
    const float* W4 = (const float*)d_in[8];
    const float* b4 = (const float*)d_in[9];
    float* out = (float*)d_out;

    const int N = in_sizes[0];         // 100000
    const int E = in_sizes[1] / 2;     // 3200000
    const int* src = eidx;
    const int* dst = eidx + E;

    // workspace layout (N*4 = 400000 and E*8 are 16B-multiples)
    char* ws = (char*)d_ws;
    unsigned int* deg  = (unsigned int*)ws;  ws += (size_t)N * 4;
    unsigned int* cur  = (unsigned int*)ws;  ws += (size_t)N * 4;
    unsigned int* off  = (unsigned int*)ws;  ws += (size_t)N * 4;
    unsigned int* bsum = (unsigned int*)ws;  ws += 4096;           // block sums (<=1024)
    float* dinv = (float*)ws;                ws += (size_t)N * 4;
    float* agg1 = (float*)ws;                ws += (size_t)N * 4;
    float* t4   = (float*)ws;                ws += (size_t)N * 4;
    uint2* csr  = (uint2*)ws;                ws += (size_t)E * 8;  // {src, coef}
    float* t2   = (float*)ws;                ws += (size_t)N * 32 * 4;
    float* agg2 = (float*)ws;                ws += (size_t)N * 32 * 4;
    // alias dead t2 region for layer-3 tensors (t2 dead after gather32)
    float* t3   = t2;
    float* agg3 = t2 + (size_t)N * 16;

    const int B = 256;
    const int nb = (N + 255) / 256;

    hipMemsetAsync(deg, 0, (size_t)N * 4, stream);
    hipMemsetAsync(cur, 0, (size_t)N * 4, stream);

    deg_kernel<<<(E + B - 1) / B, B, 0, stream>>>(dst, deg, E);
    chunk_sum_kernel<<<nb, 256, 0, stream>>>(deg, bsum, N);
    scan_bsum_kernel<<<1, 1024, 0, stream>>>(bsum, nb);
    chunk_scan_kernel<<<nb, 256, 0, stream>>>(deg, bsum, off, N);
    dinv_kernel<<<(N + B - 1) / B, B, 0, stream>>>(deg, dinv, N);
    fill_kernel<<<(E + B - 1) / B, B, 0, stream>>>(src, dst, dinv, off, cur, csr, E);

    // layer 1 (scalar agg) + transform to 32ch
    gather1_kernel<<<(N + B - 1) / B, B, 0, stream>>>(csr, off, deg, dinv, x, agg1, N);
    fused12_kernel<<<(N + 7) / 8, B, 0, stream>>>(agg1, W1, b1, W2, t2, N);
    // layer 2 (32ch agg) + transform to 16ch
    gather32_kernel<<<((size_t)N * 32 + B - 1) / B, B, 0, stream>>>(csr, off, deg, dinv, t2, agg2, N);
    fused23_kernel<<<(N + 15) / 16, B, 0, stream>>>(agg2, b2, W3, t3, N);
    // layer 3 (16ch agg) + transform to 1ch
    gather16_kernel<<<((size_t)N * 16 + B - 1) / B, B, 0, stream>>>(csr, off, deg, dinv, t3, agg3, N);
    fused34_kernel<<<(N + B - 1) / B, B, 0, stream>>>(agg3, b3, W4, t4, N);
    // layer 4 (scalar agg) -> out
    gather4_kernel<<<(N + B - 1) / B, B, 0, stream>>>(csr, off, deg, dinv, t4, b4, out, N);
}